// Round 6
// baseline (5189.395 us; speedup 1.0000x reference)
//
#include <hip/hip_runtime.h>
#include <hip/hip_bf16.h>

typedef __attribute__((ext_vector_type(8))) short short8;
typedef __attribute__((ext_vector_type(4))) float float4v;
typedef __attribute__((ext_vector_type(4))) unsigned int uint4v;
typedef unsigned short ushort_t;
typedef unsigned int uint_t;

#define BB 64      // batch
#define SS 512     // seq len
#define HH 1024    // hidden
#define AA 128     // actions
#define NWG 128    // recurrent workgroups: 512 threads, 2 col-tiles (32 cols) each

// ws layout (bytes)
#define XSW_BYTES   67108864ULL                  // [s][kk0..31][rg0..3][lane0..63][j0..7] bf16
#define WSW_BYTES   16777216ULL                  // [g0..255][kk0..63][lane][j] bf16
#define HALL_BYTES  67239936ULL                  // [slot 0..512][kk0..31][rg][lane][j] bf16 (slot s+1 = h_s)
#define XSW_OFF     0ULL
#define WSW_OFF     (XSW_OFF + XSW_BYTES)
#define HALL_OFF    (WSW_OFF + WSW_BYTES)
#define FLAGS_OFF   (HALL_OFF + HALL_BYTES)

#define MFMA __builtin_amdgcn_mfma_f32_16x16x32_bf16

__device__ __forceinline__ ushort_t f2bf(float f) {
    union { float f; uint_t u; } v; v.f = f;
    uint_t u = v.u;
    return (ushort_t)((u + 0x7fffu + ((u >> 16) & 1u)) >> 16);
}

__device__ __forceinline__ float fast_sigmoid(float x) {
    return __builtin_amdgcn_rcpf(1.0f + __expf(-x));
}
__device__ __forceinline__ float fast_tanh(float x) {
    return 1.0f - 2.0f * __builtin_amdgcn_rcpf(1.0f + __expf(2.0f * x));
}

// ---------------- init: flags, Hall[0] (h_{-1}=0), output dummy blocks ----------------
__global__ void k_init(uint_t* __restrict__ flags, ushort_t* __restrict__ hall,
                       float* __restrict__ out) {
    int i = blockIdx.x * 256 + threadIdx.x;          // 32768 threads
    if (i < NWG) flags[i] = 0u;
    ((uint_t*)hall)[i] = 0u;                          // 65536 ushorts = 32768 uints (slot 0)
    out[i] = 0.0f;                                    // dummy block 0
    out[32768 + (size_t)BB * SS * AA + i] = 0.0f;     // dummy block 2
}

// ---------------- x_emb gather + bf16 + A-fragment swizzle ----------------
__global__ void k_prep_x(const float* __restrict__ embed, const int* __restrict__ x,
                         ushort_t* __restrict__ xsw) {
    int t = blockIdx.x * 256 + threadIdx.x;          // 4,194,304 threads = [s][kk][rg][lane]
    int lane = t & 63;
    int rg   = (t >> 6) & 3;
    int kk   = (t >> 8) & 31;
    int s    = t >> 13;
    int b  = rg * 16 + (lane & 15);
    int k0 = kk * 32 + (lane >> 4) * 8;
    int tok = x[b * SS + s];
    const float* src = embed + (size_t)tok * HH + k0;
    float4v v0 = *(const float4v*)src;
    float4v v1 = *(const float4v*)(src + 4);
    uint_t p0 = (uint_t)f2bf(v0[0]) | ((uint_t)f2bf(v0[1]) << 16);
    uint_t p1 = (uint_t)f2bf(v0[2]) | ((uint_t)f2bf(v0[3]) << 16);
    uint_t p2 = (uint_t)f2bf(v1[0]) | ((uint_t)f2bf(v1[1]) << 16);
    uint_t p3 = (uint_t)f2bf(v1[2]) | ((uint_t)f2bf(v1[3]) << 16);
    uint4v pk = {p0, p1, p2, p3};
    ((uint4v*)xsw)[t] = pk;
}

// ---------------- [Wi;Wh] -> bf16, gate-interleaved cols, B-fragment swizzle ----------------
__global__ void k_prep_w(const float* __restrict__ Wi, const float* __restrict__ Wh,
                         ushort_t* __restrict__ wsw) {
    int t = blockIdx.x * 256 + threadIdx.x;          // 8,388,608 threads = [k][q][u]
    int u = t & 1023;
    int q = (t >> 10) & 3;
    int k = t >> 12;                                 // 0..2047
    float v = (k < 1024) ? Wi[(size_t)k * 4096 + q * 1024 + u]
                         : Wh[(size_t)(k - 1024) * 4096 + q * 1024 + u];
    int g = u >> 2, du = u & 3;
    int c = du * 4 + q;                              // col-in-slice 0..15
    int kk = k >> 5, quad = (k >> 3) & 3, j = k & 7;
    int lane = quad * 16 + c;
    wsw[(((size_t)g * 64 + kk) * 64 + lane) * 8 + j] = f2bf(v);
}

// ---------------- persistent sequential LSTM scan ----------------
// v1 body per wave, but 8 waves/WG: wave w -> (rg = w&3, tile = w>>2).
// Each wave's serial stream == v1 (64 MFMA, 64 loads); 2 waves/SIMD give TLP
// to hide L2 load latency. Sync mechanism identical to v1, 128 flags.
__global__ void __launch_bounds__(512)
k_lstm(const ushort_t* __restrict__ xsw, const ushort_t* __restrict__ wsw,
       ushort_t* hall, const float* __restrict__ bh, uint_t* flags) {
    __shared__ ushort_t wlds[2 * 64 * 64 * 8];       // 128 KiB: two 16-col slices
    const int g    = blockIdx.x;                     // 0..127, owns slices {2g, 2g+1}
    const int tid  = threadIdx.x;
    const int lane = tid & 63;
    const int w    = tid >> 6;                       // wave id 0..7
    const int rg   = w & 3;                          // batch row-group
    const int tle  = w >> 2;                         // col-tile 0/1

    {   // stage both weight slices (contiguous in wsw; coalesced 16B/lane)
        const uint4v* src = (const uint4v*)(wsw + (size_t)(2 * g) * 64 * 64 * 8);
        uint4v* dst = (uint4v*)wlds;
        for (int i = tid; i < 8192; i += 512) dst[i] = src[i];
    }
    __syncthreads();

    const int c_idx = lane & 15;
    const int q  = c_idx & 3;                        // gate (i,f,g,o)
    const int du = c_idx >> 2;                       // unit-within-slice
    const int quad = lane >> 4;
    const int sl = 2 * g + tle;                      // this wave's weight slice
    const int u  = sl * 4 + du;                      // hidden unit this lane group owns
    const float bhv = bh[q * 1024 + u];

    // h write coords (lanes with q==0 && du even store packed pairs)
    const int kk_h = u >> 5;
    const int quad_h = (u & 31) >> 3;
    const int j_h = u & 7;                            // even for storing lanes
    uint_t* hall32 = (uint_t*)hall;
    const short8* xbase = (const short8*)xsw;
    const short8* hbase = (const short8*)hall;
    const short8* wl = (const short8*)wlds + (tle << 12) + lane;   // tile slice base

    float cst0 = 0.f, cst1 = 0.f, cst2 = 0.f, cst3 = 0.f;  // c-state, 4 batch rows

    for (int s = 0; s < SS; ++s) {
        float4v ac0 = {bhv, bhv, bhv, bhv};
        float4v ac1 = {0.f, 0.f, 0.f, 0.f};
        float4v ac2 = {0.f, 0.f, 0.f, 0.f};
        float4v ac3 = {0.f, 0.f, 0.f, 0.f};

        // ---- x-part (no dependency on h): overlaps the flag wait below ----
        const short8* xp = xbase + (((size_t)s * 32) * 4 + rg) * 64 + lane;
        #pragma unroll
        for (int kk = 0; kk < 32; kk += 4) {
            short8 a0 = xp[(kk + 0) * 256];
            short8 a1 = xp[(kk + 1) * 256];
            short8 a2 = xp[(kk + 2) * 256];
            short8 a3 = xp[(kk + 3) * 256];
            ac0 = MFMA(a0, wl[(kk + 0) * 64], ac0, 0, 0, 0);
            ac1 = MFMA(a1, wl[(kk + 1) * 64], ac1, 0, 0, 0);
            ac2 = MFMA(a2, wl[(kk + 2) * 64], ac2, 0, 0, 0);
            ac3 = MFMA(a3, wl[(kk + 3) * 64], ac3, 0, 0, 0);
        }

        // ---- wait until all WGs finished step s-1 (flags monotone, sc1 loads) ----
        {
            bool ok;
            do {
                uint_t f = __hip_atomic_load(&flags[tid & (NWG - 1)], __ATOMIC_RELAXED,
                                             __HIP_MEMORY_SCOPE_AGENT);
                ok = (f >= (uint_t)s);
            } while (!__syncthreads_and(ok));
            asm volatile("" ::: "memory");   // no fence: h-writes traveled via sc1 (LLC)
        }

        // ---- h-part (normal cached loads; slot s is write-once, no stale copies) ----
        const short8* hp = hbase + (((size_t)s * 32) * 4 + rg) * 64 + lane;
        #pragma unroll
        for (int kk = 0; kk < 32; kk += 4) {
            short8 a0 = hp[(kk + 0) * 256];
            short8 a1 = hp[(kk + 1) * 256];
            short8 a2 = hp[(kk + 2) * 256];
            short8 a3 = hp[(kk + 3) * 256];
            ac0 = MFMA(a0, wl[(32 + kk + 0) * 64], ac0, 0, 0, 0);
            ac1 = MFMA(a1, wl[(32 + kk + 1) * 64], ac1, 0, 0, 0);
            ac2 = MFMA(a2, wl[(32 + kk + 2) * 64], ac2, 0, 0, 0);
            ac3 = MFMA(a3, wl[(32 + kk + 3) * 64], ac3, 0, 0, 0);
        }
        float4v acc = (ac0 + ac1) + (ac2 + ac3);

        // ---- elementwise LSTM update: activate own gate, then shuffle activated ----
        float hv[4];
        #pragma unroll
        for (int r = 0; r < 4; ++r) {
            float own = acc[r];
            float a = (q == 2) ? fast_tanh(own) : fast_sigmoid(own);
            float x1 = __shfl_xor(a, 1);
            float x2 = __shfl_xor(a, 2);
            float x3 = __shfl_xor(a, 3);
            float gi, gf, gg, go;
            if      (q == 0) { gi = a;  gf = x1; gg = x2; go = x3; }
            else if (q == 1) { gi = x1; gf = a;  gg = x3; go = x2; }
            else if (q == 2) { gi = x2; gf = x3; gg = a;  go = x1; }
            else             { gi = x3; gf = x2; gg = x1; go = a;  }
            float cv = (r == 0 ? cst0 : r == 1 ? cst1 : r == 2 ? cst2 : cst3);
            cv = gf * cv + gi * gg;
            if (r == 0) cst0 = cv; else if (r == 1) cst1 = cv;
            else if (r == 2) cst2 = cv; else cst3 = cv;
            hv[r] = go * fast_tanh(cv);
        }

        // ---- pack (even u, odd u) bf16 pair -> one dword sc1 store to LLC ----
        float pv0 = __shfl_xor(hv[0], 4);
        float pv1 = __shfl_xor(hv[1], 4);
        float pv2 = __shfl_xor(hv[2], 4);
        float pv3 = __shfl_xor(hv[3], 4);
        if (q == 0 && (du & 1) == 0) {
            float pv[4] = {pv0, pv1, pv2, pv3};
            size_t base = (((size_t)(s + 1) * 32 + kk_h) * 4 + rg) * 64;
            #pragma unroll
            for (int r = 0; r < 4; ++r) {
                uint_t packed = (uint_t)f2bf(hv[r]) | ((uint_t)f2bf(pv[r]) << 16);
                int lane_h = quad_h * 16 + quad * 4 + r;
                size_t idx = ((base + (size_t)lane_h) * 8 + j_h) >> 1;
                __hip_atomic_store(&hall32[idx], packed, __ATOMIC_RELAXED,
                                   __HIP_MEMORY_SCOPE_AGENT);
            }
        }
        // __syncthreads drains vmcnt(0) for ALL waves (HW release), then post flag
        __syncthreads();
        if (tid == 0)
            __hip_atomic_store(&flags[g], (uint_t)(s + 1), __ATOMIC_RELAXED,
                               __HIP_MEMORY_SCOPE_AGENT);
    }
}

// ---------------- head GEMM: logits[b][s][:] = h_s @ Wo + bo ----------------
__global__ void __launch_bounds__(256)
k_head(const ushort_t* __restrict__ hall, const float* __restrict__ Wo,
       const float* __restrict__ bo, float* __restrict__ out) {
    __shared__ ushort_t wlds[32 * 2 * 64 * 8];       // 64 KiB: [kk][nt][lane][j]
    const int wg = blockIdx.x;                       // 512 WGs: cg(4) x sg(128)
    const int cg = wg & 3, sg = wg >> 2;
    const int tid = threadIdx.x, lane = tid & 63, rg = tid >> 6;
    const int col0 = cg * 32;

    for (int i = tid; i < 32768; i += 256) {         // [k][col] -> B-frag swizzle
        int k = i >> 5;
        int col = i & 31;
        float v = Wo[(size_t)k * AA + col0 + col];
        int kk = k >> 5, quad = (k >> 3) & 3, j = k & 7;
        int nt = col >> 4, cl = col & 15;
        wlds[(((kk * 2 + nt) * 64) + quad * 16 + cl) * 8 + j] = f2bf(v);
    }
    __syncthreads();

    const int cl = lane & 15, quad = lane >> 4;
    const float bo0 = bo[col0 + cl];
    const float bo1 = bo[col0 + 16 + cl];
    const short8* wl = (const short8*)wlds + lane;

    for (int si = 0; si < 4; ++si) {
        int s = sg * 4 + si;
        float4v a0 = {bo0, bo0, bo0, bo0};
        float4v a1 = {bo1, bo1, bo1, bo1};
        const short8* hp = (const short8*)hall + (((size_t)(s + 1) * 32) * 4 + rg) * 64 + lane;
        #pragma unroll 8
        for (int kk = 0; kk < 32; ++kk) {
            short8 a = hp[kk * 256];
            a0 = MFMA(a, wl[(kk * 2 + 0) * 64], a0, 0, 0, 0);
            a1 = MFMA(a, wl[(kk * 2 + 1) * 64], a1, 0, 0, 0);
        }
        #pragma unroll
        for (int r = 0; r < 4; ++r) {
            int b = rg * 16 + quad * 4 + r;
            size_t o = 32768 + ((size_t)b * SS + s) * AA;
            out[o + col0 + cl]      = a0[r];
            out[o + col0 + 16 + cl] = a1[r];
        }
    }
}

extern "C" void kernel_launch(void* const* d_in, const int* in_sizes, int n_in,
                              void* d_out, int out_size, void* d_ws, size_t ws_size,
                              hipStream_t stream) {
    const float* embed = (const float*)d_in[0];
    const float* Wi    = (const float*)d_in[1];
    const float* Wh    = (const float*)d_in[2];
    const float* bh    = (const float*)d_in[3];
    const float* Wo    = (const float*)d_in[4];
    const float* bo    = (const float*)d_in[5];
    const int*   x     = (const int*)d_in[6];
    float* out = (float*)d_out;
    unsigned char* ws = (unsigned char*)d_ws;

    ushort_t* xsw  = (ushort_t*)(ws + XSW_OFF);
    ushort_t* wsw  = (ushort_t*)(ws + WSW_OFF);
    ushort_t* hall = (ushort_t*)(ws + HALL_OFF);
    uint_t*   flags = (uint_t*)(ws + FLAGS_OFF);

    k_init  <<<128,   256, 0, stream>>>(flags, hall, out);
    k_prep_x<<<16384, 256, 0, stream>>>(embed, x, xsw);
    k_prep_w<<<32768, 256, 0, stream>>>(Wi, Wh, wsw);
    k_lstm  <<<NWG,   512, 0, stream>>>(xsw, wsw, hall, bh, flags);
    k_head  <<<512,   256, 0, stream>>>(hall, Wo, bo, out);
}

// Round 10
// 3279.422 us; speedup vs baseline: 1.5824x; 1.5824x over previous
//
#include <hip/hip_runtime.h>
#include <hip/hip_bf16.h>

typedef __attribute__((ext_vector_type(8))) short short8;
typedef __attribute__((ext_vector_type(4))) float float4v;
typedef __attribute__((ext_vector_type(4))) unsigned int uint4v;
typedef unsigned short ushort_t;
typedef unsigned int uint_t;

#define BB 64      // batch
#define SS 512     // seq len
#define HH 1024    // hidden
#define AA 128     // actions
#define NWG 256    // recurrent workgroups (each owns 16 interleaved gate cols = 4 units)

// ws layout (bytes)
#define XSW_BYTES   67108864ULL                  // [s][kk0..31][rg0..3][lane0..63][j0..7] bf16
#define WSW_BYTES   16777216ULL                  // [g0..255][kk0..63][lane][j] bf16
#define HALL_BYTES  67239936ULL                  // [slot 0..512][kk0..31][rg][lane][j] bf16 (slot s+1 = h_s)
#define XSW_OFF     0ULL
#define WSW_OFF     (XSW_OFF + XSW_BYTES)
#define HALL_OFF    (WSW_OFF + WSW_BYTES)
#define FLAGS_OFF   (HALL_OFF + HALL_BYTES)

#define MFMA __builtin_amdgcn_mfma_f32_16x16x32_bf16

// async global->LDS, 16 B/lane: per-lane SOURCE address, wave-uniform LDS dest (+lane*16 by HW)
#define GLL16(gsrc, ldst)                                                          \
    __builtin_amdgcn_global_load_lds(                                              \
        (const __attribute__((address_space(1))) unsigned int*)(gsrc),             \
        (__attribute__((address_space(3))) unsigned int*)(ldst), 16, 0, 0)

__device__ __forceinline__ ushort_t f2bf(float f) {
    union { float f; uint_t u; } v; v.f = f;
    uint_t u = v.u;
    return (ushort_t)((u + 0x7fffu + ((u >> 16) & 1u)) >> 16);
}

__device__ __forceinline__ float fast_sigmoid(float x) {
    return __builtin_amdgcn_rcpf(1.0f + __expf(-x));
}
__device__ __forceinline__ float fast_tanh(float x) {
    return 1.0f - 2.0f * __builtin_amdgcn_rcpf(1.0f + __expf(2.0f * x));
}

// ---------------- init: flags, Hall[0] (h_{-1}=0), output dummy blocks ----------------
__global__ void k_init(uint_t* __restrict__ flags, ushort_t* __restrict__ hall,
                       float* __restrict__ out) {
    int i = blockIdx.x * 256 + threadIdx.x;          // 32768 threads
    if (i < NWG) flags[i] = 0u;
    ((uint_t*)hall)[i] = 0u;                          // 65536 ushorts = 32768 uints (slot 0)
    out[i] = 0.0f;                                    // dummy block 0
    out[32768 + (size_t)BB * SS * AA + i] = 0.0f;     // dummy block 2
}

// ---------------- x_emb gather + bf16 + A-fragment swizzle ----------------
__global__ void k_prep_x(const float* __restrict__ embed, const int* __restrict__ x,
                         ushort_t* __restrict__ xsw) {
    int t = blockIdx.x * 256 + threadIdx.x;          // 4,194,304 threads = [s][kk][rg][lane]
    int lane = t & 63;
    int rg   = (t >> 6) & 3;
    int kk   = (t >> 8) & 31;
    int s    = t >> 13;
    int b  = rg * 16 + (lane & 15);
    int k0 = kk * 32 + (lane >> 4) * 8;
    int tok = x[b * SS + s];
    const float* src = embed + (size_t)tok * HH + k0;
    float4v v0 = *(const float4v*)src;
    float4v v1 = *(const float4v*)(src + 4);
    uint_t p0 = (uint_t)f2bf(v0[0]) | ((uint_t)f2bf(v0[1]) << 16);
    uint_t p1 = (uint_t)f2bf(v0[2]) | ((uint_t)f2bf(v0[3]) << 16);
    uint_t p2 = (uint_t)f2bf(v1[0]) | ((uint_t)f2bf(v1[1]) << 16);
    uint_t p3 = (uint_t)f2bf(v1[2]) | ((uint_t)f2bf(v1[3]) << 16);
    uint4v pk = {p0, p1, p2, p3};
    ((uint4v*)xsw)[t] = pk;
}

// ---------------- [Wi;Wh] -> bf16, gate-interleaved cols, B-fragment swizzle ----------------
__global__ void k_prep_w(const float* __restrict__ Wi, const float* __restrict__ Wh,
                         ushort_t* __restrict__ wsw) {
    int t = blockIdx.x * 256 + threadIdx.x;          // 8,388,608 threads = [k][q][u]
    int u = t & 1023;
    int q = (t >> 10) & 3;
    int k = t >> 12;                                 // 0..2047
    float v = (k < 1024) ? Wi[(size_t)k * 4096 + q * 1024 + u]
                         : Wh[(size_t)(k - 1024) * 4096 + q * 1024 + u];
    int g = u >> 2, du = u & 3;
    int c = du * 4 + q;                              // col-in-slice 0..15
    int kk = k >> 5, quad = (k >> 3) & 3, j = k & 7;
    int lane = quad * 16 + c;
    wsw[(((size_t)g * 64 + kk) * 64 + lane) * 8 + j] = f2bf(v);
}

// ---------------- persistent sequential LSTM scan (v1 schedule + gll staging) ----------------
// Identical to v1 in mapping/sync/math. Only change: A-fragments arrive via
// global_load_lds (16 in flight, ONE vmcnt wait per 16-kk chunk) instead of
// VGPR loads (compiler batches of ~4, ~8 latency round-trips per part).
__global__ void __launch_bounds__(256)
k_lstm(const ushort_t* __restrict__ xsw, const ushort_t* __restrict__ wsw,
       ushort_t* hall, const float* __restrict__ bh, uint_t* flags) {
    __shared__ ushort_t wlds[65536];                 // 128 KiB = 64K weights + 4x16K stage -> 1 WG/CU
    const int g    = blockIdx.x;
    const int tid  = threadIdx.x;
    const int lane = tid & 63;
    const int rg   = tid >> 6;                       // wave id = batch row-group

    {   // stage weight slice (coalesced 16B/lane)
        const uint4v* src = (const uint4v*)(wsw + (size_t)g * 64 * 64 * 8);
        uint4v* dst = (uint4v*)wlds;
        for (int i = tid; i < 4096; i += 256) dst[i] = src[i];
    }
    __syncthreads();

    const int c_idx = lane & 15;
    const int q  = c_idx & 3;
    const int du = c_idx >> 2;
    const int quad = lane >> 4;
    const int u = g * 4 + du;                        // hidden unit this lane group owns
    const float bhv = bh[q * 1024 + u];

    // h write coords (lanes with q==0 && du even store packed pairs)
    const int kk_h = u >> 5;
    const int quad_h = (u & 31) >> 3;
    const int j_h = u & 7;                            // even for storing lanes
    uint_t* hall32 = (uint_t*)hall;
    const short8* xbase = (const short8*)xsw;
    const short8* hbase = (const short8*)hall;
    const short8* wl = (const short8*)wlds + lane;

    ushort_t* stg = wlds + 32768 + rg * 8192;        // this wave's 16 KiB stage (16 kk x 1 KiB)
    const short8* sr = (const short8*)stg;           // consume at [kc*64 + lane]

    float cst0 = 0.f, cst1 = 0.f, cst2 = 0.f, cst3 = 0.f;  // c-state, 4 batch rows

    for (int s = 0; s < SS; ++s) {
        float4v ac0 = {bhv, bhv, bhv, bhv};
        float4v ac1 = {0.f, 0.f, 0.f, 0.f};
        float4v ac2 = {0.f, 0.f, 0.f, 0.f};
        float4v ac3 = {0.f, 0.f, 0.f, 0.f};

        // ---- x-part (no dependency on h): overlaps the flag wait below ----
        const short8* xp = xbase + (((size_t)s * 32) * 4 + rg) * 64 + lane;
        #pragma unroll
        for (int c = 0; c < 2; ++c) {
            #pragma unroll
            for (int kc = 0; kc < 16; ++kc)
                GLL16(xp + (c * 16 + kc) * 256, stg + kc * 512);
            asm volatile("s_waitcnt vmcnt(0)" ::: "memory");
            #pragma unroll
            for (int kc = 0; kc < 16; kc += 4) {
                short8 a0 = sr[(kc + 0) * 64 + lane];
                short8 a1 = sr[(kc + 1) * 64 + lane];
                short8 a2 = sr[(kc + 2) * 64 + lane];
                short8 a3 = sr[(kc + 3) * 64 + lane];
                ac0 = MFMA(a0, wl[(c * 16 + kc + 0) * 64], ac0, 0, 0, 0);
                ac1 = MFMA(a1, wl[(c * 16 + kc + 1) * 64], ac1, 0, 0, 0);
                ac2 = MFMA(a2, wl[(c * 16 + kc + 2) * 64], ac2, 0, 0, 0);
                ac3 = MFMA(a3, wl[(c * 16 + kc + 3) * 64], ac3, 0, 0, 0);
            }
            // stage reads complete (data in VGPRs) before buffer reuse next chunk
            asm volatile("s_waitcnt lgkmcnt(0)" ::: "memory");
        }

        // ---- wait until all WGs finished step s-1 (flags monotone, v1 mechanism) ----
        {
            bool ok;
            do {
                uint_t f = __hip_atomic_load(&flags[tid], __ATOMIC_RELAXED,
                                             __HIP_MEMORY_SCOPE_AGENT);
                ok = (f >= (uint_t)s);
            } while (!__syncthreads_and(ok));
            asm volatile("" ::: "memory");   // no fence: h-writes traveled via sc1 (LLC)
        }

        // ---- h-part via gll staging (slot s write-once, no stale copies) ----
        const short8* hp = hbase + (((size_t)s * 32) * 4 + rg) * 64 + lane;
        #pragma unroll
        for (int c = 0; c < 2; ++c) {
            #pragma unroll
            for (int kc = 0; kc < 16; ++kc)
                GLL16(hp + (c * 16 + kc) * 256, stg + kc * 512);
            asm volatile("s_waitcnt vmcnt(0)" ::: "memory");
            #pragma unroll
            for (int kc = 0; kc < 16; kc += 4) {
                short8 a0 = sr[(kc + 0) * 64 + lane];
                short8 a1 = sr[(kc + 1) * 64 + lane];
                short8 a2 = sr[(kc + 2) * 64 + lane];
                short8 a3 = sr[(kc + 3) * 64 + lane];
                ac0 = MFMA(a0, wl[(32 + c * 16 + kc + 0) * 64], ac0, 0, 0, 0);
                ac1 = MFMA(a1, wl[(32 + c * 16 + kc + 1) * 64], ac1, 0, 0, 0);
                ac2 = MFMA(a2, wl[(32 + c * 16 + kc + 2) * 64], ac2, 0, 0, 0);
                ac3 = MFMA(a3, wl[(32 + c * 16 + kc + 3) * 64], ac3, 0, 0, 0);
            }
            asm volatile("s_waitcnt lgkmcnt(0)" ::: "memory");
        }
        float4v acc = (ac0 + ac1) + (ac2 + ac3);

        // ---- elementwise LSTM update: activate own gate, then shuffle activated ----
        float hv[4];
        #pragma unroll
        for (int r = 0; r < 4; ++r) {
            float own = acc[r];
            float a = (q == 2) ? fast_tanh(own) : fast_sigmoid(own);
            float x1 = __shfl_xor(a, 1);
            float x2 = __shfl_xor(a, 2);
            float x3 = __shfl_xor(a, 3);
            float gi, gf, gg, go;
            if      (q == 0) { gi = a;  gf = x1; gg = x2; go = x3; }
            else if (q == 1) { gi = x1; gf = a;  gg = x3; go = x2; }
            else if (q == 2) { gi = x2; gf = x3; gg = a;  go = x1; }
            else             { gi = x3; gf = x2; gg = x1; go = a;  }
            float cv = (r == 0 ? cst0 : r == 1 ? cst1 : r == 2 ? cst2 : cst3);
            cv = gf * cv + gi * gg;
            if (r == 0) cst0 = cv; else if (r == 1) cst1 = cv;
            else if (r == 2) cst2 = cv; else cst3 = cv;
            hv[r] = go * fast_tanh(cv);
        }

        // ---- pack (even u, odd u) bf16 pair -> one dword sc1 store to LLC ----
        float pv0 = __shfl_xor(hv[0], 4);
        float pv1 = __shfl_xor(hv[1], 4);
        float pv2 = __shfl_xor(hv[2], 4);
        float pv3 = __shfl_xor(hv[3], 4);
        if (q == 0 && (du & 1) == 0) {
            float pv[4] = {pv0, pv1, pv2, pv3};
            size_t base = (((size_t)(s + 1) * 32 + kk_h) * 4 + rg) * 64;
            #pragma unroll
            for (int r = 0; r < 4; ++r) {
                uint_t packed = (uint_t)f2bf(hv[r]) | ((uint_t)f2bf(pv[r]) << 16);
                int lane_h = quad_h * 16 + quad * 4 + r;
                size_t idx = ((base + (size_t)lane_h) * 8 + j_h) >> 1;
                __hip_atomic_store(&hall32[idx], packed, __ATOMIC_RELAXED,
                                   __HIP_MEMORY_SCOPE_AGENT);
            }
        }
        // __syncthreads drains vmcnt(0) for ALL waves (HW release), then post flag
        __syncthreads();
        if (tid == 0)
            __hip_atomic_store(&flags[g], (uint_t)(s + 1), __ATOMIC_RELAXED,
                               __HIP_MEMORY_SCOPE_AGENT);
    }
}

// ---------------- head GEMM: logits[b][s][:] = h_s @ Wo + bo ----------------
__global__ void __launch_bounds__(256)
k_head(const ushort_t* __restrict__ hall, const float* __restrict__ Wo,
       const float* __restrict__ bo, float* __restrict__ out) {
    __shared__ ushort_t wlds[32 * 2 * 64 * 8];       // 64 KiB: [kk][nt][lane][j]
    const int wg = blockIdx.x;                       // 512 WGs: cg(4) x sg(128)
    const int cg = wg & 3, sg = wg >> 2;
    const int tid = threadIdx.x, lane = tid & 63, rg = tid >> 6;
    const int col0 = cg * 32;

    for (int i = tid; i < 32768; i += 256) {         // [k][col] -> B-frag swizzle
        int k = i >> 5;
        int col = i & 31;
        float v = Wo[(size_t)k * AA + col0 + col];
        int kk = k >> 5, quad = (k >> 3) & 3, j = k & 7;
        int nt = col >> 4, cl = col & 15;
        wlds[(((kk * 2 + nt) * 64) + quad * 16 + cl) * 8 + j] = f2bf(v);
    }
    __syncthreads();

    const int cl = lane & 15, quad = lane >> 4;
    const float bo0 = bo[col0 + cl];
    const float bo1 = bo[col0 + 16 + cl];
    const short8* wl = (const short8*)wlds + lane;

    for (int si = 0; si < 4; ++si) {
        int s = sg * 4 + si;
        float4v a0 = {bo0, bo0, bo0, bo0};
        float4v a1 = {bo1, bo1, bo1, bo1};
        const short8* hp = (const short8*)hall + (((size_t)(s + 1) * 32) * 4 + rg) * 64 + lane;
        #pragma unroll 8
        for (int kk = 0; kk < 32; ++kk) {
            short8 a = hp[kk * 256];
            a0 = MFMA(a, wl[(kk * 2 + 0) * 64], a0, 0, 0, 0);
            a1 = MFMA(a, wl[(kk * 2 + 1) * 64], a1, 0, 0, 0);
        }
        #pragma unroll
        for (int r = 0; r < 4; ++r) {
            int b = rg * 16 + quad * 4 + r;
            size_t o = 32768 + ((size_t)b * SS + s) * AA;
            out[o + col0 + cl]      = a0[r];
            out[o + col0 + 16 + cl] = a1[r];
        }
    }
}

extern "C" void kernel_launch(void* const* d_in, const int* in_sizes, int n_in,
                              void* d_out, int out_size, void* d_ws, size_t ws_size,
                              hipStream_t stream) {
    const float* embed = (const float*)d_in[0];
    const float* Wi    = (const float*)d_in[1];
    const float* Wh    = (const float*)d_in[2];
    const float* bh    = (const float*)d_in[3];
    const float* Wo    = (const float*)d_in[4];
    const float* bo    = (const float*)d_in[5];
    const int*   x     = (const int*)d_in[6];
    float* out = (float*)d_out;
    unsigned char* ws = (unsigned char*)d_ws;

    ushort_t* xsw  = (ushort_t*)(ws + XSW_OFF);
    ushort_t* wsw  = (ushort_t*)(ws + WSW_OFF);
    ushort_t* hall = (ushort_t*)(ws + HALL_OFF);
    uint_t*   flags = (uint_t*)(ws + FLAGS_OFF);

    k_init  <<<128,   256, 0, stream>>>(flags, hall, out);
    k_prep_x<<<16384, 256, 0, stream>>>(embed, x, xsw);
    k_prep_w<<<32768, 256, 0, stream>>>(Wi, Wh, wsw);
    k_lstm  <<<NWG,   256, 0, stream>>>(xsw, wsw, hall, bh, flags);
    k_head  <<<512,   256, 0, stream>>>(hall, Wo, bo, out);
}

// Round 11
// 2765.156 us; speedup vs baseline: 1.8767x; 1.1860x over previous
//
#include <hip/hip_runtime.h>
#include <hip/hip_bf16.h>

typedef __attribute__((ext_vector_type(8))) short short8;
typedef __attribute__((ext_vector_type(4))) float float4v;
typedef __attribute__((ext_vector_type(4))) unsigned int uint4v;
typedef unsigned short ushort_t;
typedef unsigned int uint_t;

#define BB 64      // batch
#define SS 512     // seq len
#define HH 1024    // hidden
#define AA 128     // actions
#define NWG 256    // recurrent workgroups (each owns 16 interleaved gate cols = 4 units)

// ws layout (bytes)
#define XSW_BYTES   67108864ULL                  // [s][kk0..31][rg0..3][lane0..63][j0..7] bf16
#define WSW_BYTES   16777216ULL                  // [g0..255][kk0..63][lane][j] bf16
#define HALL_BYTES  67239936ULL                  // [slot 0..512][kk0..31][rg][lane][j] bf16 (slot s+1 = h_s)
#define XSW_OFF     0ULL
#define WSW_OFF     (XSW_OFF + XSW_BYTES)
#define HALL_OFF    (WSW_OFF + WSW_BYTES)
#define FLAGS_OFF   (HALL_OFF + HALL_BYTES)

#define MFMA __builtin_amdgcn_mfma_f32_16x16x32_bf16

__device__ __forceinline__ ushort_t f2bf(float f) {
    union { float f; uint_t u; } v; v.f = f;
    uint_t u = v.u;
    return (ushort_t)((u + 0x7fffu + ((u >> 16) & 1u)) >> 16);
}

__device__ __forceinline__ float fast_sigmoid(float x) {
    return __builtin_amdgcn_rcpf(1.0f + __expf(-x));
}
__device__ __forceinline__ float fast_tanh(float x) {
    return 1.0f - 2.0f * __builtin_amdgcn_rcpf(1.0f + __expf(2.0f * x));
}

// ---------------- init: flags, Hall[0] (h_{-1}=0), output dummy blocks ----------------
__global__ void k_init(uint_t* __restrict__ flags, ushort_t* __restrict__ hall,
                       float* __restrict__ out) {
    int i = blockIdx.x * 256 + threadIdx.x;          // 32768 threads
    if (i < NWG) flags[i] = 0u;
    ((uint_t*)hall)[i] = 0u;                          // 65536 ushorts = 32768 uints (slot 0)
    out[i] = 0.0f;                                    // dummy block 0
    out[32768 + (size_t)BB * SS * AA + i] = 0.0f;     // dummy block 2
}

// ---------------- x_emb gather + bf16 + A-fragment swizzle ----------------
__global__ void k_prep_x(const float* __restrict__ embed, const int* __restrict__ x,
                         ushort_t* __restrict__ xsw) {
    int t = blockIdx.x * 256 + threadIdx.x;          // 4,194,304 threads = [s][kk][rg][lane]
    int lane = t & 63;
    int rg   = (t >> 6) & 3;
    int kk   = (t >> 8) & 31;
    int s    = t >> 13;
    int b  = rg * 16 + (lane & 15);
    int k0 = kk * 32 + (lane >> 4) * 8;
    int tok = x[b * SS + s];
    const float* src = embed + (size_t)tok * HH + k0;
    float4v v0 = *(const float4v*)src;
    float4v v1 = *(const float4v*)(src + 4);
    uint_t p0 = (uint_t)f2bf(v0[0]) | ((uint_t)f2bf(v0[1]) << 16);
    uint_t p1 = (uint_t)f2bf(v0[2]) | ((uint_t)f2bf(v0[3]) << 16);
    uint_t p2 = (uint_t)f2bf(v1[0]) | ((uint_t)f2bf(v1[1]) << 16);
    uint_t p3 = (uint_t)f2bf(v1[2]) | ((uint_t)f2bf(v1[3]) << 16);
    uint4v pk = {p0, p1, p2, p3};
    ((uint4v*)xsw)[t] = pk;
}

// ---------------- [Wi;Wh] -> bf16, gate-interleaved cols, B-fragment swizzle ----------------
__global__ void k_prep_w(const float* __restrict__ Wi, const float* __restrict__ Wh,
                         ushort_t* __restrict__ wsw) {
    int t = blockIdx.x * 256 + threadIdx.x;          // 8,388,608 threads = [k][q][u]
    int u = t & 1023;
    int q = (t >> 10) & 3;
    int k = t >> 12;                                 // 0..2047
    float v = (k < 1024) ? Wi[(size_t)k * 4096 + q * 1024 + u]
                         : Wh[(size_t)(k - 1024) * 4096 + q * 1024 + u];
    int g = u >> 2, du = u & 3;
    int c = du * 4 + q;                              // col-in-slice 0..15
    int kk = k >> 5, quad = (k >> 3) & 3, j = k & 7;
    int lane = quad * 16 + c;
    wsw[(((size_t)g * 64 + kk) * 64 + lane) * 8 + j] = f2bf(v);
}

// ---------------- persistent sequential LSTM scan (v1 + unroll-8 load batching) ----------------
// Byte-identical to v1 in mapping/sync/math order. Only change: kk loops unroll 8
// (8 loads visible before first MFMA use -> ~8 loads in flight vs ~4), halving
// exposed L2 round trips. kk+i -> ac[i&3] preserves per-accumulator FP order.
__global__ void __launch_bounds__(256)
k_lstm(const ushort_t* __restrict__ xsw, const ushort_t* __restrict__ wsw,
       ushort_t* hall, const float* __restrict__ bh, uint_t* flags) {
    __shared__ ushort_t wlds[64 * 64 * 8];           // 64 KiB: [kk0..63][lane][j]
    const int g    = blockIdx.x;
    const int tid  = threadIdx.x;
    const int lane = tid & 63;
    const int rg   = tid >> 6;                       // wave id = batch row-group

    {   // stage weight slice (coalesced 16B/lane)
        const uint4v* src = (const uint4v*)(wsw + (size_t)g * 64 * 64 * 8);
        uint4v* dst = (uint4v*)wlds;
        for (int i = tid; i < 4096; i += 256) dst[i] = src[i];
    }
    __syncthreads();

    const int c_idx = lane & 15;
    const int q  = c_idx & 3;
    const int du = c_idx >> 2;
    const int quad = lane >> 4;
    const int u = g * 4 + du;                        // hidden unit this lane group owns
    const float bhv = bh[q * 1024 + u];

    // h write coords (lanes with q==0 && du even store packed pairs)
    const int kk_h = u >> 5;
    const int quad_h = (u & 31) >> 3;
    const int j_h = u & 7;                            // even for storing lanes
    uint_t* hall32 = (uint_t*)hall;

    float cst0 = 0.f, cst1 = 0.f, cst2 = 0.f, cst3 = 0.f;  // c-state, 4 batch rows
    const short8* xbase = (const short8*)xsw;
    const short8* hbase = (const short8*)hall;
    const short8* wl = (const short8*)wlds + lane;

    for (int s = 0; s < SS; ++s) {
        float4v ac0 = {bhv, bhv, bhv, bhv};
        float4v ac1 = {0.f, 0.f, 0.f, 0.f};
        float4v ac2 = {0.f, 0.f, 0.f, 0.f};
        float4v ac3 = {0.f, 0.f, 0.f, 0.f};

        // ---- x-part (no dependency on h): overlaps the flag wait below ----
        const short8* xp = xbase + (((size_t)s * 32) * 4 + rg) * 64 + lane;
        #pragma unroll
        for (int kk = 0; kk < 32; kk += 8) {
            short8 a0 = xp[(kk + 0) * 256];
            short8 a1 = xp[(kk + 1) * 256];
            short8 a2 = xp[(kk + 2) * 256];
            short8 a3 = xp[(kk + 3) * 256];
            short8 a4 = xp[(kk + 4) * 256];
            short8 a5 = xp[(kk + 5) * 256];
            short8 a6 = xp[(kk + 6) * 256];
            short8 a7 = xp[(kk + 7) * 256];
            ac0 = MFMA(a0, wl[(kk + 0) * 64], ac0, 0, 0, 0);
            ac1 = MFMA(a1, wl[(kk + 1) * 64], ac1, 0, 0, 0);
            ac2 = MFMA(a2, wl[(kk + 2) * 64], ac2, 0, 0, 0);
            ac3 = MFMA(a3, wl[(kk + 3) * 64], ac3, 0, 0, 0);
            ac0 = MFMA(a4, wl[(kk + 4) * 64], ac0, 0, 0, 0);
            ac1 = MFMA(a5, wl[(kk + 5) * 64], ac1, 0, 0, 0);
            ac2 = MFMA(a6, wl[(kk + 6) * 64], ac2, 0, 0, 0);
            ac3 = MFMA(a7, wl[(kk + 7) * 64], ac3, 0, 0, 0);
        }

        // ---- wait until all WGs finished step s-1 (flags monotone, sc1 loads) ----
        {
            bool ok;
            do {
                uint_t f = __hip_atomic_load(&flags[tid], __ATOMIC_RELAXED,
                                             __HIP_MEMORY_SCOPE_AGENT);
                ok = (f >= (uint_t)s);
            } while (!__syncthreads_and(ok));
            asm volatile("" ::: "memory");   // no fence: h-writes traveled via sc1 (LLC)
        }

        // ---- h-part (normal cached loads; slot s is write-once, no stale copies) ----
        const short8* hp = hbase + (((size_t)s * 32) * 4 + rg) * 64 + lane;
        #pragma unroll
        for (int kk = 0; kk < 32; kk += 8) {
            short8 a0 = hp[(kk + 0) * 256];
            short8 a1 = hp[(kk + 1) * 256];
            short8 a2 = hp[(kk + 2) * 256];
            short8 a3 = hp[(kk + 3) * 256];
            short8 a4 = hp[(kk + 4) * 256];
            short8 a5 = hp[(kk + 5) * 256];
            short8 a6 = hp[(kk + 6) * 256];
            short8 a7 = hp[(kk + 7) * 256];
            ac0 = MFMA(a0, wl[(32 + kk + 0) * 64], ac0, 0, 0, 0);
            ac1 = MFMA(a1, wl[(32 + kk + 1) * 64], ac1, 0, 0, 0);
            ac2 = MFMA(a2, wl[(32 + kk + 2) * 64], ac2, 0, 0, 0);
            ac3 = MFMA(a3, wl[(32 + kk + 3) * 64], ac3, 0, 0, 0);
            ac0 = MFMA(a4, wl[(32 + kk + 4) * 64], ac0, 0, 0, 0);
            ac1 = MFMA(a5, wl[(32 + kk + 5) * 64], ac1, 0, 0, 0);
            ac2 = MFMA(a6, wl[(32 + kk + 6) * 64], ac2, 0, 0, 0);
            ac3 = MFMA(a7, wl[(32 + kk + 7) * 64], ac3, 0, 0, 0);
        }
        float4v acc = (ac0 + ac1) + (ac2 + ac3);

        // ---- elementwise LSTM update: activate own gate, then shuffle activated ----
        float hv[4];
        #pragma unroll
        for (int r = 0; r < 4; ++r) {
            float own = acc[r];
            float a = (q == 2) ? fast_tanh(own) : fast_sigmoid(own);
            float x1 = __shfl_xor(a, 1);
            float x2 = __shfl_xor(a, 2);
            float x3 = __shfl_xor(a, 3);
            float gi, gf, gg, go;
            if      (q == 0) { gi = a;  gf = x1; gg = x2; go = x3; }
            else if (q == 1) { gi = x1; gf = a;  gg = x3; go = x2; }
            else if (q == 2) { gi = x2; gf = x3; gg = a;  go = x1; }
            else             { gi = x3; gf = x2; gg = x1; go = a;  }
            float cv = (r == 0 ? cst0 : r == 1 ? cst1 : r == 2 ? cst2 : cst3);
            cv = gf * cv + gi * gg;
            if (r == 0) cst0 = cv; else if (r == 1) cst1 = cv;
            else if (r == 2) cst2 = cv; else cst3 = cv;
            hv[r] = go * fast_tanh(cv);
        }

        // ---- pack (even u, odd u) bf16 pair -> one dword sc1 store to LLC ----
        float pv0 = __shfl_xor(hv[0], 4);
        float pv1 = __shfl_xor(hv[1], 4);
        float pv2 = __shfl_xor(hv[2], 4);
        float pv3 = __shfl_xor(hv[3], 4);
        if (q == 0 && (du & 1) == 0) {
            float pv[4] = {pv0, pv1, pv2, pv3};
            size_t base = (((size_t)(s + 1) * 32 + kk_h) * 4 + rg) * 64;
            #pragma unroll
            for (int r = 0; r < 4; ++r) {
                uint_t packed = (uint_t)f2bf(hv[r]) | ((uint_t)f2bf(pv[r]) << 16);
                int lane_h = quad_h * 16 + quad * 4 + r;
                size_t idx = ((base + (size_t)lane_h) * 8 + j_h) >> 1;
                __hip_atomic_store(&hall32[idx], packed, __ATOMIC_RELAXED,
                                   __HIP_MEMORY_SCOPE_AGENT);
            }
        }
        // __syncthreads drains vmcnt(0) for ALL waves (HW release), then post flag
        __syncthreads();
        if (tid == 0)
            __hip_atomic_store(&flags[g], (uint_t)(s + 1), __ATOMIC_RELAXED,
                               __HIP_MEMORY_SCOPE_AGENT);
    }
}

// ---------------- head GEMM: logits[b][s][:] = h_s @ Wo + bo ----------------
__global__ void __launch_bounds__(256)
k_head(const ushort_t* __restrict__ hall, const float* __restrict__ Wo,
       const float* __restrict__ bo, float* __restrict__ out) {
    __shared__ ushort_t wlds[32 * 2 * 64 * 8];       // 64 KiB: [kk][nt][lane][j]
    const int wg = blockIdx.x;                       // 512 WGs: cg(4) x sg(128)
    const int cg = wg & 3, sg = wg >> 2;
    const int tid = threadIdx.x, lane = tid & 63, rg = tid >> 6;
    const int col0 = cg * 32;

    for (int i = tid; i < 32768; i += 256) {         // [k][col] -> B-frag swizzle
        int k = i >> 5;
        int col = i & 31;
        float v = Wo[(size_t)k * AA + col0 + col];
        int kk = k >> 5, quad = (k >> 3) & 3, j = k & 7;
        int nt = col >> 4, cl = col & 15;
        wlds[(((kk * 2 + nt) * 64) + quad * 16 + cl) * 8 + j] = f2bf(v);
    }
    __syncthreads();

    const int cl = lane & 15, quad = lane >> 4;
    const float bo0 = bo[col0 + cl];
    const float bo1 = bo[col0 + 16 + cl];
    const short8* wl = (const short8*)wlds + lane;

    for (int si = 0; si < 4; ++si) {
        int s = sg * 4 + si;
        float4v a0 = {bo0, bo0, bo0, bo0};
        float4v a1 = {bo1, bo1, bo1, bo1};
        const short8* hp = (const short8*)hall + (((size_t)(s + 1) * 32) * 4 + rg) * 64 + lane;
        #pragma unroll 8
        for (int kk = 0; kk < 32; ++kk) {
            short8 a = hp[kk * 256];
            a0 = MFMA(a, wl[(kk * 2 + 0) * 64], a0, 0, 0, 0);
            a1 = MFMA(a, wl[(kk * 2 + 1) * 64], a1, 0, 0, 0);
        }
        #pragma unroll
        for (int r = 0; r < 4; ++r) {
            int b = rg * 16 + quad * 4 + r;
            size_t o = 32768 + ((size_t)b * SS + s) * AA;
            out[o + col0 + cl]      = a0[r];
            out[o + col0 + 16 + cl] = a1[r];
        }
    }
}

extern "C" void kernel_launch(void* const* d_in, const int* in_sizes, int n_in,
                              void* d_out, int out_size, void* d_ws, size_t ws_size,
                              hipStream_t stream) {
    const float* embed = (const float*)d_in[0];
    const float* Wi    = (const float*)d_in[1];
    const float* Wh    = (const float*)d_in[2];
    const float* bh    = (const float*)d_in[3];
    const float* Wo    = (const float*)d_in[4];
    const float* bo    = (const float*)d_in[5];
    const int*   x     = (const int*)d_in[6];
    float* out = (float*)d_out;
    unsigned char* ws = (unsigned char*)d_ws;

    ushort_t* xsw  = (ushort_t*)(ws + XSW_OFF);
    ushort_t* wsw  = (ushort_t*)(ws + WSW_OFF);
    ushort_t* hall = (ushort_t*)(ws + HALL_OFF);
    uint_t*   flags = (uint_t*)(ws + FLAGS_OFF);

    k_init  <<<128,   256, 0, stream>>>(flags, hall, out);
    k_prep_x<<<16384, 256, 0, stream>>>(embed, x, xsw);
    k_prep_w<<<32768, 256, 0, stream>>>(Wi, Wh, wsw);
    k_lstm  <<<NWG,   256, 0, stream>>>(xsw, wsw, hall, bh, flags);
    k_head  <<<512,   256, 0, stream>>>(hall, Wo, bo, out);
}